// Round 1
// baseline (139.406 us; speedup 1.0000x reference)
//
#include <hip/hip_runtime.h>
#include <math.h>

#define DIM 4096
#define INTER 11008
#define EPS 1e-5f
#define THRESH 0.05f

__device__ __forceinline__ float wave_sum(float v) {
#pragma unroll
    for (int off = 32; off > 0; off >>= 1) v += __shfl_xor(v, off, 64);
    return v;
}

// out[i] = thr( x[i] * rsqrt(mean(x^2)+eps) * w[i] ), DIM elements, 1 block x 1024 thr
__global__ __launch_bounds__(1024) void rmsnorm_thr_kernel(
        const float* __restrict__ x, const float* __restrict__ w,
        float* __restrict__ out) {
    __shared__ float red[16];
    __shared__ float s_scale;
    const int tid = threadIdx.x;
    float4 xv = reinterpret_cast<const float4*>(x)[tid];
    float ss = xv.x * xv.x + xv.y * xv.y + xv.z * xv.z + xv.w * xv.w;
    ss = wave_sum(ss);
    const int wid = tid >> 6, lane = tid & 63;
    if (lane == 0) red[wid] = ss;
    __syncthreads();
    if (tid == 0) {
        float s = 0.f;
#pragma unroll
        for (int i = 0; i < 16; ++i) s += red[i];
        s_scale = rsqrtf(s / (float)DIM + EPS);
    }
    __syncthreads();
    const float scale = s_scale;
    float4 wv = reinterpret_cast<const float4*>(w)[tid];
    float4 o;
    o.x = xv.x * scale * wv.x;
    o.y = xv.y * scale * wv.y;
    o.z = xv.z * scale * wv.z;
    o.w = xv.w * scale * wv.w;
    o.x = (fabsf(o.x) > THRESH) ? o.x : 0.f;
    o.y = (fabsf(o.y) > THRESH) ? o.y : 0.f;
    o.z = (fabsf(o.z) > THRESH) ? o.z : 0.f;
    o.w = (fabsf(o.w) > THRESH) ? o.w : 0.f;
    reinterpret_cast<float4*>(out)[tid] = o;
}

// out[row] = thr( dot(W[row,:], x) ), K=DIM. One wave per row, 4 waves/block.
__global__ __launch_bounds__(256) void gemv_thr_kernel(
        const float* __restrict__ W, const float* __restrict__ x,
        float* __restrict__ out) {
    const int lane = threadIdx.x & 63;
    const int row = (blockIdx.x << 2) + (threadIdx.x >> 6);
    const float* wr = W + (size_t)row * DIM;
    float acc = 0.f;
#pragma unroll 4
    for (int k = 0; k < DIM; k += 256) {
        float4 wv = *reinterpret_cast<const float4*>(wr + k + (lane << 2));
        float4 xv = *reinterpret_cast<const float4*>(x + k + (lane << 2));
        acc = fmaf(wv.x, xv.x, acc);
        acc = fmaf(wv.y, xv.y, acc);
        acc = fmaf(wv.z, xv.z, acc);
        acc = fmaf(wv.w, xv.w, acc);
    }
    acc = wave_sum(acc);
    if (lane == 0) out[row] = (fabsf(acc) > THRESH) ? acc : 0.f;
}

// out[row] = res[row] + dot(W[row,:], x), K=DIM
__global__ __launch_bounds__(256) void gemv_res_kernel(
        const float* __restrict__ W, const float* __restrict__ x,
        const float* __restrict__ res, float* __restrict__ out) {
    const int lane = threadIdx.x & 63;
    const int row = (blockIdx.x << 2) + (threadIdx.x >> 6);
    const float* wr = W + (size_t)row * DIM;
    float acc = 0.f;
#pragma unroll 4
    for (int k = 0; k < DIM; k += 256) {
        float4 wv = *reinterpret_cast<const float4*>(wr + k + (lane << 2));
        float4 xv = *reinterpret_cast<const float4*>(x + k + (lane << 2));
        acc = fmaf(wv.x, xv.x, acc);
        acc = fmaf(wv.y, xv.y, acc);
        acc = fmaf(wv.z, xv.z, acc);
        acc = fmaf(wv.w, xv.w, acc);
    }
    acc = wave_sum(acc);
    if (lane == 0) out[row] = res[row] + acc;
}

// out[row] = thr( silu(dot(W1[row,:],x)) * dot(W3[row,:],x) ), K=DIM, N=INTER
__global__ __launch_bounds__(256) void gateup_kernel(
        const float* __restrict__ W1, const float* __restrict__ W3,
        const float* __restrict__ x, float* __restrict__ out) {
    const int lane = threadIdx.x & 63;
    const int row = (blockIdx.x << 2) + (threadIdx.x >> 6);
    const float* w1r = W1 + (size_t)row * DIM;
    const float* w3r = W3 + (size_t)row * DIM;
    float g = 0.f, u = 0.f;
#pragma unroll 4
    for (int k = 0; k < DIM; k += 256) {
        float4 xv = *reinterpret_cast<const float4*>(x + k + (lane << 2));
        float4 av = *reinterpret_cast<const float4*>(w1r + k + (lane << 2));
        float4 bv = *reinterpret_cast<const float4*>(w3r + k + (lane << 2));
        g = fmaf(av.x, xv.x, g);
        g = fmaf(av.y, xv.y, g);
        g = fmaf(av.z, xv.z, g);
        g = fmaf(av.w, xv.w, g);
        u = fmaf(bv.x, xv.x, u);
        u = fmaf(bv.y, xv.y, u);
        u = fmaf(bv.z, xv.z, u);
        u = fmaf(bv.w, xv.w, u);
    }
    g = wave_sum(g);
    u = wave_sum(u);
    if (lane == 0) {
        float s = g / (1.f + expf(-g));   // silu
        float a = s * u;
        out[row] = (fabsf(a) > THRESH) ? a : 0.f;
    }
}

// out[row] = h[row] + dot(W2[row,:], x), K=INTER, N=DIM
__global__ __launch_bounds__(256) void down_kernel(
        const float* __restrict__ W2, const float* __restrict__ x,
        const float* __restrict__ h, float* __restrict__ out) {
    const int lane = threadIdx.x & 63;
    const int row = (blockIdx.x << 2) + (threadIdx.x >> 6);
    const float* wr = W2 + (size_t)row * INTER;
    float acc = 0.f;
#pragma unroll 4
    for (int k = 0; k < INTER; k += 256) {  // 11008 = 43 * 256, exact
        float4 wv = *reinterpret_cast<const float4*>(wr + k + (lane << 2));
        float4 xv = *reinterpret_cast<const float4*>(x + k + (lane << 2));
        acc = fmaf(wv.x, xv.x, acc);
        acc = fmaf(wv.y, xv.y, acc);
        acc = fmaf(wv.z, xv.z, acc);
        acc = fmaf(wv.w, xv.w, acc);
    }
    acc = wave_sum(acc);
    if (lane == 0) out[row] = h[row] + acc;
}

extern "C" void kernel_launch(void* const* d_in, const int* in_sizes, int n_in,
                              void* d_out, int out_size, void* d_ws, size_t ws_size,
                              hipStream_t stream) {
    // setup_inputs order: x, freqs_cis, wqkv, wo, w1, w2, w3, attn_norm_w, ffn_norm_w, mask
    const float* x    = (const float*)d_in[0];
    const float* wqkv = (const float*)d_in[2];
    const float* wo   = (const float*)d_in[3];
    const float* w1   = (const float*)d_in[4];
    const float* w2   = (const float*)d_in[5];
    const float* w3   = (const float*)d_in[6];
    const float* anw  = (const float*)d_in[7];
    const float* fnw  = (const float*)d_in[8];
    float* out = (float*)d_out;

    float* ws   = (float*)d_ws;
    float* hs   = ws;            // 4096  : thr(rmsnorm(x))
    float* vt   = ws + 4096;     // 4096  : thr(V)  (== thr(attn out), since SEQ=1 softmax==1)
    float* h    = ws + 8192;     // 4096  : x + wo·vt
    float* hft  = ws + 12288;    // 4096  : thr(rmsnorm(h))
    float* actt = ws + 16384;    // 11008 : thr(silu(gate)*up)

    // V weight block: rows [2*kv_size, 3*kv_size) of wqkv. Q/K rows are dead
    // code at SEQ=1 (softmax over 1 key == 1 -> attn output == V; RoPE at
    // position 0 is identity anyway).
    const float* wv = wqkv + (size_t)2 * 4096 * DIM;

    rmsnorm_thr_kernel<<<1, 1024, 0, stream>>>(x, anw, hs);
    gemv_thr_kernel  <<<DIM / 4, 256, 0, stream>>>(wv, hs, vt);
    gemv_res_kernel  <<<DIM / 4, 256, 0, stream>>>(wo, vt, x, h);
    rmsnorm_thr_kernel<<<1, 1024, 0, stream>>>(h, fnw, hft);
    gateup_kernel    <<<INTER / 4, 256, 0, stream>>>(w1, w3, hft, actt);
    down_kernel      <<<DIM / 4, 256, 0, stream>>>(w2, actt, h, out);
}

// Round 2
// 132.916 us; speedup vs baseline: 1.0488x; 1.0488x over previous
//
#include <hip/hip_runtime.h>
#include <math.h>

#define DIM 4096
#define INTER 11008
#define EPS 1e-5f
#define THRESH 0.05f

__device__ __forceinline__ float wave_sum(float v) {
#pragma unroll
    for (int off = 32; off > 0; off >>= 1) v += __shfl_xor(v, off, 64);
    return v;
}

// Per-wave RMS scale of a DIM-length vector (each wave computes it
// redundantly from L2-resident x; avoids a separate 1-block kernel +
// launch on the critical path).
__device__ __forceinline__ float wave_rms_scale(const float* __restrict__ x,
                                                int lane) {
    float ss = 0.f;
#pragma unroll
    for (int k = 0; k < DIM; k += 256) {
        float4 v = *reinterpret_cast<const float4*>(x + k + (lane << 2));
        ss = fmaf(v.x, v.x, ss);
        ss = fmaf(v.y, v.y, ss);
        ss = fmaf(v.z, v.z, ss);
        ss = fmaf(v.w, v.w, ss);
    }
    ss = wave_sum(ss);
    return rsqrtf(ss * (1.f / (float)DIM) + EPS);
}

__device__ __forceinline__ float thr(float v) {
    return (fabsf(v) > THRESH) ? v : 0.f;
}

// out[row] = thr( dot(W[row,:], thr(rmsnorm(x)*nw)) )
// One wave per row, 4 rows/block. K = DIM.
__global__ __launch_bounds__(256) void gemv_rms_thr_kernel(
        const float* __restrict__ W, const float* __restrict__ x,
        const float* __restrict__ nw, float* __restrict__ out) {
    const int lane = threadIdx.x & 63;
    const int row = (blockIdx.x << 2) + (threadIdx.x >> 6);
    const float scale = wave_rms_scale(x, lane);
    const float* wr = W + (size_t)row * DIM;
    float acc[4] = {0.f, 0.f, 0.f, 0.f};
    for (int k = 0; k < DIM; k += 1024) {
#pragma unroll
        for (int u = 0; u < 4; ++u) {
            const int kk = k + (u << 8) + (lane << 2);
            float4 wv = *reinterpret_cast<const float4*>(wr + kk);
            float4 xv = *reinterpret_cast<const float4*>(x + kk);
            float4 nv = *reinterpret_cast<const float4*>(nw + kk);
            float x0 = thr(xv.x * scale * nv.x);
            float x1 = thr(xv.y * scale * nv.y);
            float x2 = thr(xv.z * scale * nv.z);
            float x3 = thr(xv.w * scale * nv.w);
            acc[u] = fmaf(wv.x, x0, acc[u]);
            acc[u] = fmaf(wv.y, x1, acc[u]);
            acc[u] = fmaf(wv.z, x2, acc[u]);
            acc[u] = fmaf(wv.w, x3, acc[u]);
        }
    }
    float a = (acc[0] + acc[1]) + (acc[2] + acc[3]);
    a = wave_sum(a);
    if (lane == 0) out[row] = thr(a);
}

// out[row] = res[row] + dot(W[row,:], x), K = DIM (x pre-thresholded)
__global__ __launch_bounds__(256) void gemv_res_kernel(
        const float* __restrict__ W, const float* __restrict__ x,
        const float* __restrict__ res, float* __restrict__ out) {
    const int lane = threadIdx.x & 63;
    const int row = (blockIdx.x << 2) + (threadIdx.x >> 6);
    const float* wr = W + (size_t)row * DIM;
    float acc[4] = {0.f, 0.f, 0.f, 0.f};
    for (int k = 0; k < DIM; k += 1024) {
#pragma unroll
        for (int u = 0; u < 4; ++u) {
            const int kk = k + (u << 8) + (lane << 2);
            float4 wv = *reinterpret_cast<const float4*>(wr + kk);
            float4 xv = *reinterpret_cast<const float4*>(x + kk);
            acc[u] = fmaf(wv.x, xv.x, acc[u]);
            acc[u] = fmaf(wv.y, xv.y, acc[u]);
            acc[u] = fmaf(wv.z, xv.z, acc[u]);
            acc[u] = fmaf(wv.w, xv.w, acc[u]);
        }
    }
    float a = (acc[0] + acc[1]) + (acc[2] + acc[3]);
    a = wave_sum(a);
    if (lane == 0) out[row] = res[row] + a;
}

// hn = thr(rmsnorm(h)*nw) computed inline per wave;
// out[row] = thr( silu(dot(W1[row,:],hn)) * dot(W3[row,:],hn) ), N = INTER
__global__ __launch_bounds__(256) void gateup_rms_kernel(
        const float* __restrict__ W1, const float* __restrict__ W3,
        const float* __restrict__ h, const float* __restrict__ nw,
        float* __restrict__ out) {
    const int lane = threadIdx.x & 63;
    const int row = (blockIdx.x << 2) + (threadIdx.x >> 6);
    const float scale = wave_rms_scale(h, lane);
    const float* w1r = W1 + (size_t)row * DIM;
    const float* w3r = W3 + (size_t)row * DIM;
    float g[2] = {0.f, 0.f}, u[2] = {0.f, 0.f};
    for (int k = 0; k < DIM; k += 512) {
#pragma unroll
        for (int p = 0; p < 2; ++p) {
            const int kk = k + (p << 8) + (lane << 2);
            float4 hv = *reinterpret_cast<const float4*>(h + kk);
            float4 nv = *reinterpret_cast<const float4*>(nw + kk);
            float4 av = *reinterpret_cast<const float4*>(w1r + kk);
            float4 bv = *reinterpret_cast<const float4*>(w3r + kk);
            float x0 = thr(hv.x * scale * nv.x);
            float x1 = thr(hv.y * scale * nv.y);
            float x2 = thr(hv.z * scale * nv.z);
            float x3 = thr(hv.w * scale * nv.w);
            g[p] = fmaf(av.x, x0, g[p]);
            g[p] = fmaf(av.y, x1, g[p]);
            g[p] = fmaf(av.z, x2, g[p]);
            g[p] = fmaf(av.w, x3, g[p]);
            u[p] = fmaf(bv.x, x0, u[p]);
            u[p] = fmaf(bv.y, x1, u[p]);
            u[p] = fmaf(bv.z, x2, u[p]);
            u[p] = fmaf(bv.w, x3, u[p]);
        }
    }
    float gg = wave_sum(g[0] + g[1]);
    float uu = wave_sum(u[0] + u[1]);
    if (lane == 0) {
        float s = gg / (1.f + expf(-gg));  // silu
        out[row] = thr(s * uu);
    }
}

// out[row] = h[row] + dot(W2[row,:], x), K = INTER (x pre-thresholded)
__global__ __launch_bounds__(256) void down_kernel(
        const float* __restrict__ W2, const float* __restrict__ x,
        const float* __restrict__ h, float* __restrict__ out) {
    const int lane = threadIdx.x & 63;
    const int row = (blockIdx.x << 2) + (threadIdx.x >> 6);
    const float* wr = W2 + (size_t)row * INTER;
    float acc[4] = {0.f, 0.f, 0.f, 0.f};
    // 11008 = 10*1024 + 768
    int k = 0;
    for (; k + 1024 <= INTER; k += 1024) {
#pragma unroll
        for (int u = 0; u < 4; ++u) {
            const int kk = k + (u << 8) + (lane << 2);
            float4 wv = *reinterpret_cast<const float4*>(wr + kk);
            float4 xv = *reinterpret_cast<const float4*>(x + kk);
            acc[u] = fmaf(wv.x, xv.x, acc[u]);
            acc[u] = fmaf(wv.y, xv.y, acc[u]);
            acc[u] = fmaf(wv.z, xv.z, acc[u]);
            acc[u] = fmaf(wv.w, xv.w, acc[u]);
        }
    }
#pragma unroll
    for (int u = 0; u < 3; ++u) {  // tail 768 = 3*256
        const int kk = k + (u << 8) + (lane << 2);
        float4 wv = *reinterpret_cast<const float4*>(wr + kk);
        float4 xv = *reinterpret_cast<const float4*>(x + kk);
        acc[u] = fmaf(wv.x, xv.x, acc[u]);
        acc[u] = fmaf(wv.y, xv.y, acc[u]);
        acc[u] = fmaf(wv.z, xv.z, acc[u]);
        acc[u] = fmaf(wv.w, xv.w, acc[u]);
    }
    float a = (acc[0] + acc[1]) + (acc[2] + acc[3]);
    a = wave_sum(a);
    if (lane == 0) out[row] = h[row] + a;
}

extern "C" void kernel_launch(void* const* d_in, const int* in_sizes, int n_in,
                              void* d_out, int out_size, void* d_ws, size_t ws_size,
                              hipStream_t stream) {
    // setup_inputs order: x, freqs_cis, wqkv, wo, w1, w2, w3, attn_norm_w, ffn_norm_w, mask
    const float* x    = (const float*)d_in[0];
    const float* wqkv = (const float*)d_in[2];
    const float* wo   = (const float*)d_in[3];
    const float* w1   = (const float*)d_in[4];
    const float* w2   = (const float*)d_in[5];
    const float* w3   = (const float*)d_in[6];
    const float* anw  = (const float*)d_in[7];
    const float* fnw  = (const float*)d_in[8];
    float* out = (float*)d_out;

    float* ws   = (float*)d_ws;
    float* vt   = ws;            // 4096  : thr(V)  (SEQ=1 -> softmax==1 -> attn out == V)
    float* h    = ws + 4096;     // 4096  : x + wo·vt
    float* actt = ws + 8192;     // 11008 : thr(silu(gate)*up)

    // V weight block: rows [2*kv_size, 3*kv_size) of wqkv. Q/K rows are dead
    // code at SEQ=1 (softmax over 1 key == 1; RoPE at position 0 is identity).
    const float* wv = wqkv + (size_t)2 * 4096 * DIM;

    gemv_rms_thr_kernel<<<DIM / 4, 256, 0, stream>>>(wv, x, anw, vt);
    gemv_res_kernel    <<<DIM / 4, 256, 0, stream>>>(wo, vt, x, h);
    gateup_rms_kernel  <<<INTER / 4, 256, 0, stream>>>(w1, w3, h, fnw, actt);
    down_kernel        <<<DIM / 4, 256, 0, stream>>>(w2, actt, h, out);
}